// Round 6
// baseline (6462.740 us; speedup 1.0000x reference)
//
#include <hip/hip_runtime.h>

// Problem constants (reference: B=2, T=2048, C=1024, V=8192, L=2, H=16, d=64)
#define BB 2
#define TT 2048
#define CC 1024
#define VV 8192
#define LL 2
#define HH 16
#define DD 64
#define MM (BB * TT) // 4096 rows

// R6 plan:
//  - GEMMs on MFMA bf16 (weights pre-converted fp32->bf16 each launch).
//  - Flash: 1 wave / 32 queries, lane=(query, dim-half) -> qr[32]+acc[32],
//    ~100 VGPR (R5 had 256 -> occupancy-starved), shfl_xor(32) combines halves.
// Memory plan:
//  d_out [0,8M) h | [8,16M) q/ctx | [16,24M) k | [24,32M) v   (bf16, ours)
//        [32,48M) WB: Wq,Wk,Wv,Wo converted bf16 (dead at logits time)
//  embed_w buffer (>=16MB both modes; consumed by embed at step 0):
//        [0,16M) WuB converted bf16
//  d_ws  [0,8M) hScr bf16 | [8M,+16K) nll fp32 | +flag int   (~8.02 MB)
using u16 = unsigned short;
typedef __attribute__((ext_vector_type(8))) short short8;
typedef __attribute__((ext_vector_type(4))) float f32x4;

__device__ __forceinline__ float bf2f(u16 u) {
    union { unsigned int i; float f; } x;
    x.i = ((unsigned int)u) << 16;
    return x.f;
}
__device__ __forceinline__ u16 f2bf(float f) {
    union { float f; unsigned int i; } x;
    x.f = f;
    unsigned int r = x.i + 0x7fffu + ((x.i >> 16) & 1u); // round-to-nearest-even
    return (u16)(r >> 16);
}
__device__ __forceinline__ float lo16(unsigned int u) {
    union { unsigned int i; float f; } x; x.i = u << 16; return x.f;
}
__device__ __forceinline__ float hi16(unsigned int u) {
    union { unsigned int i; float f; } x; x.i = u & 0xffff0000u; return x.f;
}
__device__ __forceinline__ unsigned int pack2(float a, float b) {
    return (unsigned int)f2bf(a) | (((unsigned int)f2bf(b)) << 16);
}

// ---------- 0. dtype probe (fp32-vs-bf16 inputs, resolved at runtime) ----------
__global__ __launch_bounds__(256) void probe_kernel(const u16* __restrict__ w,
                                                    int* __restrict__ flag) {
    __shared__ int cnt;
    if (threadIdx.x == 0) cnt = 0;
    __syncthreads();
    int c = 0;
    for (int i = threadIdx.x; i < 4096; i += 256) {
        const u16 u = w[2 * i];
        const int e = (u >> 7) & 0xff;
        if (e >= 125) ++c;
    }
    atomicAdd(&cnt, c);
    __syncthreads();
    if (threadIdx.x == 0) *flag = (cnt > 64) ? 1 : 0;
}

// ---------- 0b. weight conversion: fp32(or bf16 copy) -> bf16, 8 elems/thread ----------
__global__ __launch_bounds__(256) void convert_kernel(const void* __restrict__ src,
                                                      u16* __restrict__ dst,
                                                      const int* __restrict__ flagp) {
    const int f = *flagp;
    const size_t i = ((size_t)blockIdx.x * 256 + threadIdx.x) * 8;
    if (f) {
        const float4* s = (const float4*)src;
        float4 a = s[i / 4], b = s[i / 4 + 1];
        uint4 o;
        o.x = pack2(a.x, a.y); o.y = pack2(a.z, a.w);
        o.z = pack2(b.x, b.y); o.w = pack2(b.z, b.w);
        *(uint4*)&dst[i] = o;
    } else {
        *(uint4*)&dst[i] = ((const uint4*)src)[i / 8];
    }
}

// ---------- 1. embedding + positional -> bf16 h ----------
__global__ __launch_bounds__(256) void embed_kernel(const int* __restrict__ x,
                                                    const void* __restrict__ ew,
                                                    const void* __restrict__ pos,
                                                    u16* __restrict__ h,
                                                    const int* __restrict__ flagp) {
    const int f = *flagp;
    const int i = blockIdx.x;        // token row 0..MM-1
    const int t = i & (TT - 1);      // position within sequence
    const int row = x[i];
    const int c = threadIdx.x * 4;
    float4 e, p;
    if (f) {
        e = *(const float4*)((const float*)ew + (size_t)row * CC + c);
        p = *(const float4*)((const float*)pos + (size_t)t * CC + c);
    } else {
        ushort4 eu = *(const ushort4*)((const u16*)ew + (size_t)row * CC + c);
        ushort4 pu = *(const ushort4*)((const u16*)pos + (size_t)t * CC + c);
        e = make_float4(bf2f(eu.x), bf2f(eu.y), bf2f(eu.z), bf2f(eu.w));
        p = make_float4(bf2f(pu.x), bf2f(pu.y), bf2f(pu.z), bf2f(pu.w));
    }
    ushort4 o;
    o.x = f2bf(e.x + p.x); o.y = f2bf(e.y + p.y);
    o.z = f2bf(e.z + p.z); o.w = f2bf(e.w + p.w);
    *(ushort4*)&h[(size_t)i * CC + c] = o;
}

// ---------- 2. MFMA GEMM: out[m,n] = sum_k A[m,k]*B[n,k] (+bias[n]) (+res[m,n]) ----------
// A,B bf16 row-major. 128x128 tile, BK=32, 256 thr = 4 waves, each wave 64x64
// (4x4 grid of 16x16x32 mfma). LDS row stride 40 bf16: 16B-aligned b128 reads,
// <=2-way bank aliasing. Fragment maps (verified m89/m120):
//   A/B frag: [row = lane&15][k = (lane>>4)*8 + j]
//   C/D     : row = (lane>>4)*4 + reg, col = lane&15
#define LDR 40
__global__ __launch_bounds__(256) void gemm_mfma(const u16* __restrict__ A,
                                                 const u16* __restrict__ B,
                                                 void* __restrict__ outP,
                                                 const void* __restrict__ bias, size_t bOff,
                                                 const u16* __restrict__ res,
                                                 int M, int N, int K, int outFlagged,
                                                 const int* __restrict__ flagp) {
    const int f = *flagp;
    __shared__ u16 As[128 * LDR];
    __shared__ u16 Bs[128 * LDR];
    const int t = threadIdx.x;
    const int m0 = blockIdx.y * 128, n0 = blockIdx.x * 128;
    const int w = t >> 6, lane = t & 63;
    const int wy = w >> 1, wx = w & 1;
    const int l15 = lane & 15, quad = lane >> 4;
    const int srow = t >> 2, sch = (t & 3) * 8;   // staging: row 0..63(+64), k-chunk

    const f32x4 zero = {0.f, 0.f, 0.f, 0.f};
    f32x4 acc[4][4];
#pragma unroll
    for (int i = 0; i < 4; ++i)
#pragma unroll
        for (int j = 0; j < 4; ++j) acc[i][j] = zero;

    for (int kt = 0; kt < K; kt += 32) {
        uint4 a0 = *(const uint4*)&A[(size_t)(m0 + srow) * K + kt + sch];
        uint4 a1 = *(const uint4*)&A[(size_t)(m0 + 64 + srow) * K + kt + sch];
        uint4 b0 = *(const uint4*)&B[(size_t)(n0 + srow) * K + kt + sch];
        uint4 b1 = *(const uint4*)&B[(size_t)(n0 + 64 + srow) * K + kt + sch];
        __syncthreads();   // previous iter's frag reads done before overwrite
        *(uint4*)&As[srow * LDR + sch] = a0;
        *(uint4*)&As[(64 + srow) * LDR + sch] = a1;
        *(uint4*)&Bs[srow * LDR + sch] = b0;
        *(uint4*)&Bs[(64 + srow) * LDR + sch] = b1;
        __syncthreads();
        short8 af[4], bf[4];
#pragma unroll
        for (int bi = 0; bi < 4; ++bi)
            af[bi] = *(const short8*)&As[(wy * 64 + bi * 16 + l15) * LDR + quad * 8];
#pragma unroll
        for (int bj = 0; bj < 4; ++bj)
            bf[bj] = *(const short8*)&Bs[(wx * 64 + bj * 16 + l15) * LDR + quad * 8];
#pragma unroll
        for (int bi = 0; bi < 4; ++bi)
#pragma unroll
            for (int bj = 0; bj < 4; ++bj)
                acc[bi][bj] = __builtin_amdgcn_mfma_f32_16x16x32_bf16(
                    af[bi], bf[bj], acc[bi][bj], 0, 0, 0);
    }

#pragma unroll
    for (int bj = 0; bj < 4; ++bj) {
        const int n = n0 + wx * 64 + bj * 16 + l15;
        float bv = 0.f;
        if (bias)
            bv = f ? ((const float*)bias)[bOff + n] : bf2f(((const u16*)bias)[bOff + n]);
#pragma unroll
        for (int bi = 0; bi < 4; ++bi) {
            const int mb = m0 + wy * 64 + bi * 16 + quad * 4;
#pragma unroll
            for (int r = 0; r < 4; ++r) {
                const int m = mb + r;
                float vv = acc[bi][bj][r] + bv;
                if (res) vv += bf2f(res[(size_t)m * N + n]);
                if (outFlagged && f) ((float*)outP)[(size_t)m * N + n] = vv;
                else ((u16*)outP)[(size_t)m * N + n] = f2bf(vv);
            }
        }
    }
}

// ---------- 3. flash attention: 1 wave = 32 queries x 2 dim-halves ----------
// grid = (B*H, T/32), blockIdx.y reversed (heavy first). lane=(qi, half):
// qi=lane&31, half=lane>>5. Score = own-half dot + shfl_xor(.,32).
// K/V staged per 16-row chunk into 4KB LDS (broadcast reads).
__global__ __launch_bounds__(64) void flash2(const u16* __restrict__ q,
                                             const u16* __restrict__ k,
                                             const u16* __restrict__ v,
                                             u16* __restrict__ ctx) {
    const int bh = blockIdx.x, b = bh >> 4, hd = bh & 15;
    const int qt = (int)gridDim.y - 1 - blockIdx.y;
    const int q0 = qt * 32;
    const int lane = threadIdx.x, qi = lane & 31, half = lane >> 5;
    const int qrow = q0 + qi;
    const float scale = 0.125f;   // 1/sqrt(64)

    __shared__ u16 Ks[16 * 64];
    __shared__ u16 Vs[16 * 64];

    const u16* qp = q + ((size_t)(b * TT + qrow)) * CC + hd * DD + half * 32;
    float qr[32];
#pragma unroll
    for (int j8 = 0; j8 < 4; ++j8) {
        uint4 u = *(const uint4*)&qp[j8 * 8];
        qr[j8 * 8 + 0] = lo16(u.x); qr[j8 * 8 + 1] = hi16(u.x);
        qr[j8 * 8 + 2] = lo16(u.y); qr[j8 * 8 + 3] = hi16(u.y);
        qr[j8 * 8 + 4] = lo16(u.z); qr[j8 * 8 + 5] = hi16(u.z);
        qr[j8 * 8 + 6] = lo16(u.w); qr[j8 * 8 + 7] = hi16(u.w);
    }
    float acc[32] = {};
    float m = -1e30f, l = 0.f;

    const int nrows = q0 + 32;
    for (int c0 = 0; c0 < nrows; c0 += 16) {
        // stage 16x64 K,V (bf16): 128 chunks of 16B over 64 lanes x 2 iters
#pragma unroll
        for (int it = 0; it < 2; ++it) {
            const int idx = it * 64 + lane;     // 0..127
            const int row = idx >> 3, seg = (idx & 7) * 8;
            const size_t g = ((size_t)(b * TT + c0 + row)) * CC + hd * DD + seg;
            *(uint4*)&Ks[row * 64 + seg] = *(const uint4*)&k[g];
            *(uint4*)&Vs[row * 64 + seg] = *(const uint4*)&v[g];
        }
        __syncthreads();

        float s[16];
#pragma unroll
        for (int i = 0; i < 16; ++i) {
            float p0 = 0.f, p1 = 0.f, p2 = 0.f, p3 = 0.f;
#pragma unroll
            for (int j8 = 0; j8 < 4; ++j8) {
                uint4 kk = *(const uint4*)&Ks[i * 64 + half * 32 + j8 * 8];
                p0 += qr[j8 * 8 + 0] * lo16(kk.x); p1 += qr[j8 * 8 + 1] * hi16(kk.x);
                p2 += qr[j8 * 8 + 2] * lo16(kk.y); p3 += qr[j8 * 8 + 3] * hi16(kk.y);
                p0 += qr[j8 * 8 + 4] * lo16(kk.z); p1 += qr[j8 * 8 + 5] * hi16(kk.z);
                p2 += qr[j8 * 8 + 6] * lo16(kk.w); p3 += qr[j8 * 8 + 7] * hi16(kk.w);
            }
            const float partial = (p0 + p1) + (p2 + p3);
            const float full = partial + __shfl_xor(partial, 32);
            s[i] = (c0 + i <= qrow) ? full * scale : -1e30f;
        }
        float bm = s[0];
#pragma unroll
        for (int i = 1; i < 16; ++i) bm = fmaxf(bm, s[i]);
        const float mnew = fmaxf(m, bm);
        const float corr = __expf(m - mnew);
        l *= corr;
#pragma unroll
        for (int j = 0; j < 32; ++j) acc[j] *= corr;
#pragma unroll
        for (int i = 0; i < 16; ++i) {
            const float p = (s[i] > -1e29f) ? __expf(s[i] - mnew) : 0.f;
            l += p;
#pragma unroll
            for (int j8 = 0; j8 < 4; ++j8) {
                uint4 vv = *(const uint4*)&Vs[i * 64 + half * 32 + j8 * 8];
                acc[j8 * 8 + 0] += p * lo16(vv.x); acc[j8 * 8 + 1] += p * hi16(vv.x);
                acc[j8 * 8 + 2] += p * lo16(vv.y); acc[j8 * 8 + 3] += p * hi16(vv.y);
                acc[j8 * 8 + 4] += p * lo16(vv.z); acc[j8 * 8 + 5] += p * hi16(vv.z);
                acc[j8 * 8 + 6] += p * lo16(vv.w); acc[j8 * 8 + 7] += p * hi16(vv.w);
            }
        }
        m = mnew;
        __syncthreads();
    }

    const float inv = 1.0f / l;
    u16* cp = ctx + ((size_t)(b * TT + qrow)) * CC + hd * DD + half * 32;
#pragma unroll
    for (int j8 = 0; j8 < 4; ++j8) {
        uint4 o;
        o.x = pack2(acc[j8 * 8 + 0] * inv, acc[j8 * 8 + 1] * inv);
        o.y = pack2(acc[j8 * 8 + 2] * inv, acc[j8 * 8 + 3] * inv);
        o.z = pack2(acc[j8 * 8 + 4] * inv, acc[j8 * 8 + 5] * inv);
        o.w = pack2(acc[j8 * 8 + 6] * inv, acc[j8 * 8 + 7] * inv);
        *(uint4*)&cp[j8 * 8] = o;
    }
}

// ---------- 4. d2d copy (h -> d_ws scratch), 16B per thread ----------
__global__ __launch_bounds__(256) void copy16_kernel(const uint4* __restrict__ src,
                                                     uint4* __restrict__ dst) {
    const size_t i = (size_t)blockIdx.x * 256 + threadIdx.x;
    dst[i] = src[i];
}

// ---------- 5. loss: per-row logsumexp + NLL ----------
__global__ __launch_bounds__(256) void loss_row(const void* __restrict__ logits,
                                                const int* __restrict__ target,
                                                float* __restrict__ nll,
                                                const int* __restrict__ flagp) {
    const int f = *flagp;
    const int r = blockIdx.x;
    __shared__ float red[4];
    const float* lpf = (const float*)logits + (size_t)r * VV;
    const u16*   lpb = (const u16*)logits + (size_t)r * VV;

    float lmax = -1e30f;
    if (f) { for (int i = threadIdx.x; i < VV; i += 256) lmax = fmaxf(lmax, lpf[i]); }
    else   { for (int i = threadIdx.x; i < VV; i += 256) lmax = fmaxf(lmax, bf2f(lpb[i])); }
#pragma unroll
    for (int off = 32; off > 0; off >>= 1) lmax = fmaxf(lmax, __shfl_down(lmax, off, 64));
    const int wid = threadIdx.x >> 6, lid = threadIdx.x & 63;
    if (lid == 0) red[wid] = lmax;
    __syncthreads();
    lmax = fmaxf(fmaxf(red[0], red[1]), fmaxf(red[2], red[3]));

    float sum = 0.f;
    if (f) { for (int i = threadIdx.x; i < VV; i += 256) sum += __expf(lpf[i] - lmax); }
    else   { for (int i = threadIdx.x; i < VV; i += 256) sum += __expf(bf2f(lpb[i]) - lmax); }
#pragma unroll
    for (int off = 32; off > 0; off >>= 1) sum += __shfl_down(sum, off, 64);
    __syncthreads();
    if (lid == 0) red[wid] = sum;
    __syncthreads();
    if (threadIdx.x == 0) {
        const float s = red[0] + red[1] + red[2] + red[3];
        const float tl = f ? lpf[target[r]] : bf2f(lpb[target[r]]);
        nll[r] = lmax + __logf(s) - tl;   // = -(log_softmax at target)
    }
}

__global__ __launch_bounds__(256) void loss_final(const float* __restrict__ nll,
                                                  void* __restrict__ out,
                                                  const int* __restrict__ flagp) {
    __shared__ float red[4];
    float s = 0.f;
    for (int i = threadIdx.x; i < MM; i += 256) s += nll[i];
#pragma unroll
    for (int off = 32; off > 0; off >>= 1) s += __shfl_down(s, off, 64);
    if ((threadIdx.x & 63) == 0) red[threadIdx.x >> 6] = s;
    __syncthreads();
    if (threadIdx.x == 0) {
        const float t = (red[0] + red[1] + red[2] + red[3]) / (float)MM;
        if (*flagp) ((float*)out)[(size_t)MM * VV] = t;
        else        ((u16*)out)[(size_t)MM * VV] = f2bf(t);
    }
}

// ---------- launch ----------
extern "C" void kernel_launch(void* const* d_in, const int* in_sizes, int n_in,
                              void* d_out, int out_size, void* d_ws, size_t ws_size,
                              hipStream_t stream) {
    const int* x      = (const int*)d_in[0];
    const int* target = (const int*)d_in[1];
    const void* ew  = d_in[2];
    const void* pos = d_in[3];
    const void* Wq  = d_in[4];
    const void* bq  = d_in[5];
    const void* Wk  = d_in[6];
    const void* bk  = d_in[7];
    const void* Wv  = d_in[8];
    const void* bv  = d_in[9];
    const void* Wo  = d_in[10];
    const void* bo  = d_in[11];
    const void* Wu  = d_in[12];

    // d_ws: hScr (8MB) | nll (16KB) | flag
    char* wsb = (char*)d_ws;
    u16*   hScr  = (u16*)wsb;
    float* nll   = (float*)(wsb + 8u * 1024 * 1024);
    int*   flagp = (int*)(wsb + 8u * 1024 * 1024 + 16 * 1024 + 64);

    // d_out scratch: activations [0,32M), converted qkvo weights [32,48M)
    u16* outw = (u16*)d_out;
    u16* hB  = outw;
    u16* qB  = outw + (size_t)1 * MM * CC;
    u16* kB  = outw + (size_t)2 * MM * CC;
    u16* vB  = outw + (size_t)3 * MM * CC;
    u16* ctx = qB;  // flash lane writes exactly the (row, head-half) it read
    u16* WB  = outw + (size_t)4 * MM * CC;   // 8M elems (16 MB)
    u16* WqB = WB + (size_t)0 * LL * CC * CC;
    u16* WkB = WB + (size_t)1 * LL * CC * CC;
    u16* WvB = WB + (size_t)2 * LL * CC * CC;
    u16* WoB = WB + (size_t)3 * LL * CC * CC;
    // Wu bf16 -> embed_w buffer (16 MB usable in both modes; dead after embed)
    u16* WuB = (u16*)ew;

    probe_kernel<<<1, 256, 0, stream>>>((const u16*)Wu, flagp);
    embed_kernel<<<MM, 256, 0, stream>>>(x, ew, pos, hB, flagp);  // last read of ew

    const int gW = (LL * CC * CC) / 2048;     // 1024 blocks per qkvo array
    convert_kernel<<<gW, 256, 0, stream>>>(Wq, WqB, flagp);
    convert_kernel<<<gW, 256, 0, stream>>>(Wk, WkB, flagp);
    convert_kernel<<<gW, 256, 0, stream>>>(Wv, WvB, flagp);
    convert_kernel<<<gW, 256, 0, stream>>>(Wo, WoB, flagp);
    convert_kernel<<<(VV * CC) / 2048, 256, 0, stream>>>(Wu, WuB, flagp);

    const dim3 gP(CC / 128, MM / 128);   // projection GEMMs: 8 x 32 blocks
    for (int l = 0; l < LL; ++l) {
        const size_t wOff = (size_t)l * CC * CC, bOff = (size_t)l * CC;
        gemm_mfma<<<gP, 256, 0, stream>>>(hB, WqB + wOff, qB, bq, bOff, nullptr, MM, CC, CC, 0, flagp);
        gemm_mfma<<<gP, 256, 0, stream>>>(hB, WkB + wOff, kB, bk, bOff, nullptr, MM, CC, CC, 0, flagp);
        gemm_mfma<<<gP, 256, 0, stream>>>(hB, WvB + wOff, vB, bv, bOff, nullptr, MM, CC, CC, 0, flagp);
        flash2<<<dim3(BB * HH, TT / 32), 64, 0, stream>>>(qB, kB, vB, ctx);
        // out-proj + residual, in-place into hB
        gemm_mfma<<<gP, 256, 0, stream>>>(ctx, WoB + wOff, hB, bo, bOff, hB, MM, CC, CC, 0, flagp);
    }

    // move h out of d_out, then logits GEMM overwrites d_out (dtype per flag)
    copy16_kernel<<<(MM * CC * 2 / 16) / 256, 256, 0, stream>>>((const uint4*)hB, (uint4*)hScr);
    gemm_mfma<<<dim3(VV / 128, MM / 128), 256, 0, stream>>>(hScr, WuB, d_out,
                                                            nullptr, 0, nullptr, MM, VV, CC, 1, flagp);
    loss_row<<<MM, 256, 0, stream>>>(d_out, target, nll, flagp);
    loss_final<<<1, 256, 0, stream>>>(nll, d_out, flagp);
}